// Round 6
// baseline (5285.572 us; speedup 1.0000x reference)
//
#include <hip/hip_runtime.h>

static constexpr int HID  = 4096;  // hidden size
static constexpr int SEQL = 40;
static constexpr int OUTN = 128;
static constexpr int NBLK = 256;   // grid=256 proven cooperative-launchable (R1/R3/R4)

// Native clang vectors (HIP_vector_type structs are rejected by
// __builtin_nontemporal_*).
typedef float    nfloat4 __attribute__((ext_vector_type(4)));
typedef unsigned nuint4  __attribute__((ext_vector_type(4)));

// ---------- fp32 -> bf16 (RNE) conversion ----------
__device__ __forceinline__ unsigned f2bf(float f) {
    unsigned u = __float_as_uint(f);
    return (u + 0x7fffu + ((u >> 16) & 1u)) >> 16;
}

// Packs 8 floats -> 8 bf16 per iter; nontemporal so output doesn't dirty L2
// (R4 showed the dirty bf16 writing back 134 MB during the lstm dispatch).
__global__ void convert_w_kernel(const nfloat4* __restrict__ w,
                                 nuint4* __restrict__ o, int n8) {
    int stride = gridDim.x * blockDim.x;
    for (int i = blockIdx.x * blockDim.x + threadIdx.x; i < n8; i += stride) {
        nfloat4 a = __builtin_nontemporal_load(w + 2 * i);
        nfloat4 b = __builtin_nontemporal_load(w + 2 * i + 1);
        nuint4 r;
        r.x = f2bf(a.x) | (f2bf(a.y) << 16);
        r.y = f2bf(a.z) | (f2bf(a.w) << 16);
        r.z = f2bf(b.x) | (f2bf(b.y) << 16);
        r.w = f2bf(b.z) | (f2bf(b.w) << 16);
        __builtin_nontemporal_store(r, o + i);
    }
}

// Zero h0|h1|ctr region (contiguous dwords at start of ws).
__global__ void init_ws_kernel(unsigned* __restrict__ p, int n) {
    int i = blockIdx.x * blockDim.x + threadIdx.x;
    if (i < n) p[i] = 0u;
}

// ---------- helpers ----------
__device__ __forceinline__ float bflo(unsigned u) { return __uint_as_float(u << 16); }
__device__ __forceinline__ float bfhi(unsigned u) { return __uint_as_float(u & 0xffff0000u); }

__device__ __forceinline__ float dot8_bf(uint4 w, float4 ha, float4 hb, float acc) {
    acc = fmaf(bflo(w.x), ha.x, acc);
    acc = fmaf(bfhi(w.x), ha.y, acc);
    acc = fmaf(bflo(w.y), ha.z, acc);
    acc = fmaf(bfhi(w.y), ha.w, acc);
    acc = fmaf(bflo(w.z), hb.x, acc);
    acc = fmaf(bfhi(w.z), hb.y, acc);
    acc = fmaf(bflo(w.w), hb.z, acc);
    acc = fmaf(bfhi(w.w), hb.w, acc);
    return acc;
}

__device__ __forceinline__ float dot8_f32(float4 wa, float4 wb, float4 ha, float4 hb, float acc) {
    acc = fmaf(wa.x, ha.x, acc);
    acc = fmaf(wa.y, ha.y, acc);
    acc = fmaf(wa.z, ha.z, acc);
    acc = fmaf(wa.w, ha.w, acc);
    acc = fmaf(wb.x, hb.x, acc);
    acc = fmaf(wb.y, hb.y, acc);
    acc = fmaf(wb.z, hb.z, acc);
    acc = fmaf(wb.w, hb.w, acc);
    return acc;
}

__device__ __forceinline__ float sigm(float x) { return 1.0f / (1.0f + expf(-x)); }

// Stage the 16KB h vector into LDS via MALL-coherent atomic loads.
// 512 threads x 8 floats each.
__device__ __forceinline__ void stage_h(float* __restrict__ hsh,
                                        const float* __restrict__ hsrc) {
    int base = threadIdx.x * 8;
#pragma unroll
    for (int k = 0; k < 8; ++k)
        hsh[base + k] = __hip_atomic_load(hsrc + base + k, __ATOMIC_RELAXED,
                                          __HIP_MEMORY_SCOPE_AGENT);
}

// ---------- persistent LSTM, hand-rolled MALL barrier ----------
// 256 blocks x 512 threads = 2048 waves; each wave owns 2 hidden units
// (j, j+2048) = 8 gate rows. __launch_bounds__(512,2): 2 waves/EU min ->
// VGPR cap 256 (1024-thread blocks pinned VGPR=64 across R1/R3/R4 and the
// resulting spill-reload vmcnt(0)s capped BW at ~1.4 TB/s).
template <bool BF16>
__global__ void __launch_bounds__(512, 2)
lstm_kernel(const float* __restrict__ x,
            const float* __restrict__ w_ih,
            const float* __restrict__ b_ih,
            const float* __restrict__ b_hh,
            const void*  __restrict__ whh,
            const float* __restrict__ dense_w,
            const float* __restrict__ dense_b,
            float* __restrict__ h0,
            float* __restrict__ h1,
            unsigned* __restrict__ ctr,
            float* __restrict__ out) {
    __shared__ float hsh[HID];  // 16 KB staged h
    const int lane = threadIdx.x & 63;
    const int wave = (blockIdx.x << 3) | (threadIdx.x >> 6);  // 0..2047
    const int j0 = wave;          // unit A
    const int j1 = wave + 2048;   // unit B

    // Per-gate constants (i,f,g,o) for both units
    float wihA[4], bbA[4], wihB[4], bbB[4];
#pragma unroll
    for (int g = 0; g < 4; ++g) {
        wihA[g] = w_ih[g * HID + j0];
        bbA[g]  = b_ih[g * HID + j0] + b_hh[g * HID + j0];
        wihB[g] = w_ih[g * HID + j1];
        bbB[g]  = b_ih[g * HID + j1] + b_hh[g * HID + j1];
    }

    const uint4*  p[8];
    const float4* q[8];
    if constexpr (BF16) {
        const unsigned short* wb = (const unsigned short*)whh;
#pragma unroll
        for (int g = 0; g < 4; ++g) {
            p[g]     = (const uint4*)(wb + (size_t)(g * HID + j0) * HID) + lane;
            p[4 + g] = (const uint4*)(wb + (size_t)(g * HID + j1) * HID) + lane;
        }
    } else {
        const float* wf = (const float*)whh;
#pragma unroll
        for (int g = 0; g < 4; ++g) {
            q[g]     = (const float4*)(wf + (size_t)(g * HID + j0) * HID);
            q[4 + g] = (const float4*)(wf + (size_t)(g * HID + j1) * HID);
        }
    }

    float cA = 0.0f, cB = 0.0f;

    for (int t = 0; t < SEQL; ++t) {
        const float* hr = (t & 1) ? h1 : h0;   // t=0 reads h0 (zeroed)
        float*       hw = (t & 1) ? h0 : h1;

        stage_h(hsh, hr);
        __syncthreads();

        const float4* hv = (const float4*)hsh;
        float xt = x[t];
        float acc[8];
#pragma unroll
        for (int r = 0; r < 8; ++r) acc[r] = 0.f;

        if constexpr (BF16) {
            // depth-2 weight prefetch, 8 rows; h just-in-time from LDS.
            uint4 wc[8], wn[8];
#pragma unroll
            for (int r = 0; r < 8; ++r) wc[r] = p[r][0];
#pragma unroll
            for (int it = 0; it < 8; ++it) {
                if (it < 7) {
                    int ni = (it + 1) * 64;
#pragma unroll
                    for (int r = 0; r < 8; ++r) wn[r] = p[r][ni];
                }
                float4 ha = hv[it * 128 + lane * 2];
                float4 hb = hv[it * 128 + lane * 2 + 1];
#pragma unroll
                for (int r = 0; r < 8; ++r) acc[r] = dot8_bf(wc[r], ha, hb, acc[r]);
#pragma unroll
                for (int r = 0; r < 8; ++r) wc[r] = wn[r];
            }
        } else {
#pragma unroll
            for (int it = 0; it < 8; ++it) {
                int i0 = it * 128 + lane * 2;
                float4 ha = hv[i0], hb = hv[i0 + 1];
#pragma unroll
                for (int r = 0; r < 8; ++r)
                    acc[r] = dot8_f32(q[r][i0], q[r][i0 + 1], ha, hb, acc[r]);
            }
        }

#pragma unroll
        for (int off = 32; off; off >>= 1) {
#pragma unroll
            for (int r = 0; r < 8; ++r) acc[r] += __shfl_xor(acc[r], off, 64);
        }

        float giA = acc[0] + wihA[0] * xt + bbA[0];
        float gfA = acc[1] + wihA[1] * xt + bbA[1];
        float ggA = acc[2] + wihA[2] * xt + bbA[2];
        float goA = acc[3] + wihA[3] * xt + bbA[3];
        cA = sigm(gfA) * cA + sigm(giA) * tanhf(ggA);
        float hnA = sigm(goA) * tanhf(cA);

        float giB = acc[4] + wihB[0] * xt + bbB[0];
        float gfB = acc[5] + wihB[1] * xt + bbB[1];
        float ggB = acc[6] + wihB[2] * xt + bbB[2];
        float goB = acc[7] + wihB[3] * xt + bbB[3];
        cB = sigm(gfB) * cB + sigm(giB) * tanhf(ggB);
        float hnB = sigm(goB) * tanhf(cB);

        if (lane == 0) {
            __hip_atomic_store(hw + j0, hnA, __ATOMIC_RELAXED, __HIP_MEMORY_SCOPE_AGENT);
            __hip_atomic_store(hw + j1, hnB, __ATOMIC_RELAXED, __HIP_MEMORY_SCOPE_AGENT);
        }

        // ---- hand-rolled device barrier for step t ----
        __syncthreads();   // drains each wave's AGENT-scope h stores
        if (threadIdx.x == 0) {
            __hip_atomic_fetch_add(ctr + t, 1u, __ATOMIC_RELEASE, __HIP_MEMORY_SCOPE_AGENT);
            while (__hip_atomic_load(ctr + t, __ATOMIC_RELAXED, __HIP_MEMORY_SCOPE_AGENT)
                   < (unsigned)NBLK)
                __builtin_amdgcn_s_sleep(2);
        }
        __syncthreads();
    }

    // Final h in h0 (t=39 wrote h0). Dense epilogue: blocks 0..15, one row/wave.
    if (blockIdx.x < OUTN / 8) {
        stage_h(hsh, h0);
        __syncthreads();
        int row = (blockIdx.x << 3) | (threadIdx.x >> 6);  // 0..127
        const float4* hv  = (const float4*)hsh;
        const float4* dwr = (const float4*)(dense_w + (size_t)row * HID);
        float acc = 0.f;
#pragma unroll
        for (int it = 0; it < 8; ++it) {
            int i0 = it * 128 + lane * 2;
            acc = dot8_f32(dwr[i0], dwr[i0 + 1], hv[i0], hv[i0 + 1], acc);
        }
#pragma unroll
        for (int off = 32; off; off >>= 1) acc += __shfl_xor(acc, off, 64);
        if (lane == 0) out[row] = acc + dense_b[row];
    }
}

extern "C" void kernel_launch(void* const* d_in, const int* in_sizes, int n_in,
                              void* d_out, int out_size, void* d_ws, size_t ws_size,
                              hipStream_t stream) {
    const float* x       = (const float*)d_in[0];
    const float* w_ih    = (const float*)d_in[1];
    const float* w_hh    = (const float*)d_in[2];
    const float* b_ih    = (const float*)d_in[3];
    const float* b_hh    = (const float*)d_in[4];
    const float* dense_w = (const float*)d_in[5];
    const float* dense_b = (const float*)d_in[6];
    float* out = (float*)d_out;

    // ws layout: h0[4096] f32 | h1[4096] f32 | ctr[64] u32 | wbf bf16[4*H*H]
    float*    h0  = (float*)d_ws;
    float*    h1  = h0 + HID;
    unsigned* ctr = (unsigned*)(h1 + HID);
    unsigned short* wbf = (unsigned short*)(ctr + 64);

    int nz = 2 * HID + 64;
    init_ws_kernel<<<(nz + 1023) / 1024, 1024, 0, stream>>>((unsigned*)d_ws, nz);

    size_t need = (size_t)(2 * HID + 64) * 4 + (size_t)4 * HID * HID * sizeof(unsigned short);
    bool use_bf16 = ws_size >= need;

    if (use_bf16) {
        int n8 = 4 * HID * HID / 8;
        convert_w_kernel<<<2048, 256, 0, stream>>>((const nfloat4*)w_hh, (nuint4*)wbf, n8);
        const void* wptr = (const void*)wbf;
        void* args[] = {(void*)&x, (void*)&w_ih, (void*)&b_ih, (void*)&b_hh,
                        (void*)&wptr, (void*)&dense_w, (void*)&dense_b,
                        (void*)&h0, (void*)&h1, (void*)&ctr, (void*)&out};
        void* fn = (void*)lstm_kernel<true>;
        (void)hipLaunchCooperativeKernel(fn, dim3(NBLK), dim3(512), args, 0, stream);
    } else {
        const void* wptr = (const void*)w_hh;
        void* args[] = {(void*)&x, (void*)&w_ih, (void*)&b_ih, (void*)&b_hh,
                        (void*)&wptr, (void*)&dense_w, (void*)&dense_b,
                        (void*)&h0, (void*)&h1, (void*)&ctr, (void*)&out};
        void* fn = (void*)lstm_kernel<false>;
        (void)hipLaunchCooperativeKernel(fn, dim3(NBLK), dim3(512), args, 0, stream);
    }
}